// Round 5
// baseline (322.921 us; speedup 1.0000x reference)
//
#include <hip/hip_runtime.h>
#include <math.h>

// ---------------------------------------------------------------------------
// CrossAttention: B=8, N=M=2048, C=512, H=4, D=128, shared QKV weights (K==V)
// Pipeline (4 dispatches):
//   wconv2   : W_qkv,W_proj fp32 [k][n] -> bf16 [n][k] ws
//   gemm_bt  : [Q;KV] = [F1;F2](fp32) @ W + b  (bf16 ws; KV also written
//              transposed per-(b,h) as KVt[d][key] for attn V staging)
//   cross_attn: X = softmax2(Q KV^T) KV    (all staging via global_load_lds)
//   gemm_bt  : out = Xb @ Wp + bp          (fp32)
// ---------------------------------------------------------------------------

typedef __attribute__((ext_vector_type(8))) short s16x8;   // 8 bf16 = 4 VGPR
typedef __attribute__((ext_vector_type(4))) float f32x4;   // MFMA acc

#define C_DIM 512
#define HDIM  128
#define NROWS 16384           // B*N = B*M
#define SCALE_Q 0.04419417382415922f
#define LOG2E   1.4426950408889634f

__device__ __forceinline__ unsigned short f2bf(float f) {
    union { float f; unsigned u; } v; v.f = f;
    unsigned r = v.u + 0x7fffu + ((v.u >> 16) & 1u);   // RNE
    return (unsigned short)(r >> 16);
}

// async global->LDS, 16B per lane; lds dest = wave-uniform base + lane*16
__device__ __forceinline__ void async16(const void* g, void* l) {
    __builtin_amdgcn_global_load_lds(
        (const __attribute__((address_space(1))) void*)g,
        (__attribute__((address_space(3))) void*)l, 16, 0, 0);
}

// ---------------------------------------------------------------------------
// W [k][n] fp32 -> Wt [n][k] bf16 (512x512), 64x64 tiles; z selects pair
// ---------------------------------------------------------------------------
__global__ __launch_bounds__(256)
void wconv_t2(const float* __restrict__ W0, const float* __restrict__ W1,
              unsigned short* __restrict__ T0, unsigned short* __restrict__ T1) {
    const float* W = blockIdx.z ? W1 : W0;
    unsigned short* Wt = blockIdx.z ? T1 : T0;
    __shared__ float t[64][65];
    const int k0 = blockIdx.y * 64, n0 = blockIdx.x * 64;
    const int c = threadIdx.x & 63, r0 = threadIdx.x >> 6;
#pragma unroll
    for (int r = r0; r < 64; r += 4)
        t[r][c] = W[(size_t)(k0 + r) * C_DIM + n0 + c];
    __syncthreads();
#pragma unroll
    for (int r = r0; r < 64; r += 4)
        Wt[(size_t)(n0 + r) * C_DIM + k0 + c] = f2bf(t[c][r]);
}

// ---------------------------------------------------------------------------
// GEMM: C[rows x 512] = A[rows x 512] @ Wt^T + bias.
// 128x128 tile, BK=64 (8 k-iters). Bs staged via async16 (bf16).
// A_FP32: A read fp32 (F1 rows <topRows, F2 rest), converted during manual
// staging (XOR chunk swizzle pos = c ^ (row&7), matching frag reads).
// WRITE_KVT: KV-half epilogue also writes KVt[b][h][d][key] (uint2 of 4
// consecutive keys) for attn's async V staging.
// ---------------------------------------------------------------------------
template <int A_FP32, int WRITE_KVT, int OUT_BF16>
__global__ __launch_bounds__(256, 3)
void gemm_bt(const unsigned short* __restrict__ Abf,
             const float* __restrict__ Af1, const float* __restrict__ Af2,
             const unsigned short* __restrict__ Bt,
             const float* __restrict__ bias,
             void* __restrict__ Cv, unsigned short* __restrict__ KVt,
             float oscTop, int topRows) {
    __shared__ __align__(16) unsigned short As[128][64];
    __shared__ __align__(16) unsigned short Bs[128][64];

    const int tid  = threadIdx.x;
    const int wid  = tid >> 6;
    const int lane = tid & 63;
    const int lr   = lane & 15;
    const int quad = lane >> 4;
    const int wm   = wid >> 1;
    const int wn   = wid & 1;
    const int rowBase = blockIdx.y * 128;
    const int colBase = blockIdx.x * 128;
    const int srow = lane >> 3;
    const int soff = srow * C_DIM + (((lane & 7) ^ (srow & 7)) * 8);
    const float osc = (rowBase < topRows) ? oscTop : 1.0f;
    const float* Afp = (A_FP32 && rowBase < topRows)
                           ? (Af1 + (size_t)rowBase * C_DIM)
                           : (Af2 + (size_t)(rowBase - topRows) * C_DIM);

    f32x4 acc[4][4];
#pragma unroll
    for (int i = 0; i < 4; i++)
#pragma unroll
        for (int j = 0; j < 4; j++) acc[i][j] = (f32x4)0.0f;

    for (int kt = 0; kt < 8; kt++) {
        const int k0 = kt * 64;
        __syncthreads();
        if (A_FP32) {
#pragma unroll
            for (int i = 0; i < 4; i++) {
                const int chunkid = tid + 256 * i;   // 1024 chunks: 128r x 8c
                const int row = chunkid >> 3, c = chunkid & 7;
                const int pos = c ^ (row & 7);
                const float* p = Afp + (size_t)row * C_DIM + k0 + c * 8;
                float4 v0 = *(const float4*)p;
                float4 v1 = *(const float4*)(p + 4);
                union { unsigned short us[8]; uint4 v; } o;
                o.us[0] = f2bf(v0.x); o.us[1] = f2bf(v0.y);
                o.us[2] = f2bf(v0.z); o.us[3] = f2bf(v0.w);
                o.us[4] = f2bf(v1.x); o.us[5] = f2bf(v1.y);
                o.us[6] = f2bf(v1.z); o.us[7] = f2bf(v1.w);
                *(uint4*)&As[row][pos * 8] = o.v;
            }
        } else {
#pragma unroll
            for (int i = 0; i < 4; i++) {
                const int R = wid * 32 + i * 8;      // wave-uniform
                async16(Abf + (size_t)(rowBase + R) * C_DIM + k0 + soff, &As[R][0]);
            }
        }
#pragma unroll
        for (int i = 0; i < 4; i++) {
            const int R = wid * 32 + i * 8;
            async16(Bt + (size_t)(colBase + R) * C_DIM + k0 + soff, &Bs[R][0]);
        }
        __syncthreads();   // drains vmcnt+lgkmcnt before frag reads

#pragma unroll
        for (int s = 0; s < 2; s++) {
            s16x8 af[4], bf[4];
#pragma unroll
            for (int i = 0; i < 4; i++)
                af[i] = *(const s16x8*)&As[wm * 64 + i * 16 + lr][((s * 4 + quad) ^ (lr & 7)) * 8];
#pragma unroll
            for (int j = 0; j < 4; j++)
                bf[j] = *(const s16x8*)&Bs[wn * 64 + j * 16 + lr][((s * 4 + quad) ^ (lr & 7)) * 8];
#pragma unroll
            for (int i = 0; i < 4; i++)
#pragma unroll
                for (int j = 0; j < 4; j++)
                    acc[i][j] = __builtin_amdgcn_mfma_f32_16x16x32_bf16(af[i], bf[j], acc[i][j], 0, 0, 0);
        }
    }

    // epilogue: C/D layout row = quad*4+r, col = lane&15
    const int isKV = WRITE_KVT && (rowBase >= topRows);
    const int rk0  = rowBase - topRows;
    const int bKV  = (rk0 >> 11);
    const int keyB = (rk0 & 2047) + wm * 64 + quad * 4;
    float bcol[4];
#pragma unroll
    for (int j = 0; j < 4; j++)
        bcol[j] = bias[colBase + wn * 64 + j * 16 + lr];
#pragma unroll
    for (int i = 0; i < 4; i++) {
#pragma unroll
        for (int j = 0; j < 4; j++) {
            const int col = colBase + wn * 64 + j * 16 + lr;
            const int row = rowBase + wm * 64 + i * 16 + quad * 4;
            float v[4];
#pragma unroll
            for (int r = 0; r < 4; r++)
                v[r] = (acc[i][j][r] + bcol[j]) * osc;
            if (OUT_BF16) {
                unsigned short* Cb = (unsigned short*)Cv;
#pragma unroll
                for (int r = 0; r < 4; r++)
                    Cb[(size_t)(row + r) * C_DIM + col] = f2bf(v[r]);
            } else {
                float* Cf = (float*)Cv;
#pragma unroll
                for (int r = 0; r < 4; r++)
                    Cf[(size_t)(row + r) * C_DIM + col] = v[r];
            }
            if (isKV) {
                const int h = col >> 7, d = col & 127;
                uint2 pk;
                pk.x = (unsigned)f2bf(v[0]) | ((unsigned)f2bf(v[1]) << 16);
                pk.y = (unsigned)f2bf(v[2]) | ((unsigned)f2bf(v[3]) << 16);
                *(uint2*)&KVt[((size_t)(bKV * 4 + h) * 128 + d) * 2048 + keyB + i * 16] = pk;
            }
        }
    }
}

// ---------------------------------------------------------------------------
// Flash cross-attention v5. Grid (N/128, H, B), 256 thr, 4 waves, 32 q/wave.
// ALL staging via global_load_lds width-16 (no VGPR round-trip, no VALU
// unpack): Kt[64][128] from KV with kappa row-permutation + XOR chunk
// swizzle at the global source; Vt[128][64] from the pre-transposed KVt.
// Key remap: S column n of MFMA j <-> key 4n+j (row R holds key
// kappa(R)=4(R&15)+(R>>4)), so P probs pack into one b64 Pl write.
// Fixed-max softmax (Q pre-scaled by SCALE*log2e).
// ---------------------------------------------------------------------------
__global__ __launch_bounds__(256, 3)
void cross_attn(const unsigned short* __restrict__ Q,
                const unsigned short* __restrict__ KV,
                const unsigned short* __restrict__ KVt,
                unsigned short* __restrict__ X) {
    __shared__ __align__(16) unsigned short Kt[64][128];   // [row][d] swizzled
    __shared__ __align__(16) unsigned short Vt[128][64];   // [d][key] swizzled
    __shared__ __align__(16) unsigned short Pl[4][32][72]; // per-wave P[q][key]

    const int tid  = threadIdx.x;
    const int wid  = tid >> 6;
    const int lane = tid & 63;
    const int lr   = lane & 15;
    const int quad = lane >> 4;
    const int b    = blockIdx.z;
    const int h    = blockIdx.y;
    const int hoff = h * HDIM;
    const size_t qrow0  = (size_t)b * 2048 + blockIdx.x * 128 + wid * 32;
    const size_t kvrow0 = (size_t)b * 2048;
    const unsigned short* KVtbh = KVt + ((size_t)(b * 4 + h) * 128) * 2048;

    // Kt staging geometry (per async16 call: 4 rows of 256B)
    const int ktR   = lane >> 4;                 // row within call
    const int ktp   = lane & 15;                 // chunk pos
    // Vt staging geometry (per async16 call: 8 rows of 128B)
    const int vtR   = lane >> 3;
    const int vtp   = lane & 7;

    // Q fragments (pre-scaled by SCALE*log2e): A[m=lr][k=kk*32+quad*8+j]
    s16x8 qf[2][4];
#pragma unroll
    for (int i = 0; i < 2; i++)
#pragma unroll
        for (int kk = 0; kk < 4; kk++)
            qf[i][kk] = *(const s16x8*)(Q + (qrow0 + i * 16 + lr) * C_DIM + hoff + kk * 32 + quad * 8);

    f32x4 O[2][8];
#pragma unroll
    for (int i = 0; i < 2; i++)
#pragma unroll
        for (int dt = 0; dt < 8; dt++) O[i][dt] = (f32x4)0.0f;
    float lacc[2][4];
#pragma unroll
    for (int i = 0; i < 2; i++)
#pragma unroll
        for (int r = 0; r < 4; r++) lacc[i][r] = 0.0f;

    for (int kt = 0; kt < 32; kt++) {
        const int key0 = kt * 64;
        __syncthreads();
        // Kt: row R holds key kappa(R), chunk pos p holds global chunk
        // (p&8)|((p&7)^(R&7))
#pragma unroll
        for (int i = 0; i < 4; i++) {
            const int Rb = (wid * 4 + i) * 4;            // wave-uniform
            const int R  = Rb + ktR;
            const int kapR = 4 * (R & 15) + (R >> 4);
            const int sc = (ktp & 8) | ((ktp & 7) ^ (R & 7));
            async16(KV + (kvrow0 + key0 + kapR) * C_DIM + hoff + sc * 8, &Kt[Rb][0]);
        }
        // Vt: row d, chunk pos p holds global key-chunk p^(d&7)
#pragma unroll
        for (int i = 0; i < 4; i++) {
            const int Rb = (wid * 4 + i) * 8;            // wave-uniform
            const int R  = Rb + vtR;
            const int c  = vtp ^ (R & 7);
            async16(KVtbh + (size_t)R * 2048 + key0 + c * 8, &Vt[Rb][0]);
        }
        __syncthreads();

        // S = Q KV^T : 32 MFMAs; MFMA j covers keys 4n+j
        f32x4 s[2][4];
#pragma unroll
        for (int i = 0; i < 2; i++)
#pragma unroll
            for (int j = 0; j < 4; j++) s[i][j] = (f32x4)0.0f;
#pragma unroll
        for (int kk = 0; kk < 4; kk++) {
#pragma unroll
            for (int j = 0; j < 4; j++) {
                s16x8 kf = *(const s16x8*)&Kt[j * 16 + lr][((kk * 4 + quad) ^ (lr & 7)) * 8];
                s[0][j] = __builtin_amdgcn_mfma_f32_16x16x32_bf16(qf[0][kk], kf, s[0][j], 0, 0, 0);
                s[1][j] = __builtin_amdgcn_mfma_f32_16x16x32_bf16(qf[1][kk], kf, s[1][j], 0, 0, 0);
            }
        }

        // fixed-max softmax + packed b64 P write (keys 4lr..4lr+3)
#pragma unroll
        for (int i = 0; i < 2; i++) {
#pragma unroll
            for (int r = 0; r < 4; r++) {
                float p0 = exp2f(s[i][0][r]);
                float p1 = exp2f(s[i][1][r]);
                float p2 = exp2f(s[i][2][r]);
                float p3 = exp2f(s[i][3][r]);
                lacc[i][r] += (p0 + p1) + (p2 + p3);
                uint2 pk;
                pk.x = (unsigned)f2bf(p0) | ((unsigned)f2bf(p1) << 16);
                pk.y = (unsigned)f2bf(p2) | ((unsigned)f2bf(p3) << 16);
                *(uint2*)&Pl[wid][i * 16 + quad * 4 + r][4 * lr] = pk;
            }
        }

        // O += P V   (wave-local LDS round-trip; DS pipe is in-order)
#pragma unroll
        for (int kk = 0; kk < 2; kk++) {
            s16x8 pa0 = *(const s16x8*)&Pl[wid][lr][kk * 32 + quad * 8];
            s16x8 pa1 = *(const s16x8*)&Pl[wid][16 + lr][kk * 32 + quad * 8];
#pragma unroll
            for (int dt = 0; dt < 8; dt++) {
                s16x8 vf = *(const s16x8*)&Vt[dt * 16 + lr][((kk * 4 + quad) ^ (lr & 7)) * 8];
                O[0][dt] = __builtin_amdgcn_mfma_f32_16x16x32_bf16(pa0, vf, O[0][dt], 0, 0, 0);
                O[1][dt] = __builtin_amdgcn_mfma_f32_16x16x32_bf16(pa1, vf, O[1][dt], 0, 0, 0);
            }
        }
    }

    // final l reduction (16 lanes of the quad-row group) + write X
#pragma unroll
    for (int i = 0; i < 2; i++) {
#pragma unroll
        for (int r = 0; r < 4; r++) {
            float l = lacc[i][r];
#pragma unroll
            for (int off = 1; off < 16; off <<= 1)
                l += __shfl_xor(l, off);
            const float inv = 1.0f / l;
            const size_t row = (qrow0 + i * 16 + quad * 4 + r) * C_DIM + hoff;
#pragma unroll
            for (int dt = 0; dt < 8; dt++)
                X[row + dt * 16 + lr] = f2bf(O[i][dt][r] * inv);
        }
    }
}

// ---------------------------------------------------------------------------
extern "C" void kernel_launch(void* const* d_in, const int* in_sizes, int n_in,
                              void* d_out, int out_size, void* d_ws, size_t ws_size,
                              hipStream_t stream) {
    const float* F1     = (const float*)d_in[0];
    const float* F2     = (const float*)d_in[1];
    const float* W_qkv  = (const float*)d_in[2];
    const float* b_qkv  = (const float*)d_in[3];
    const float* W_proj = (const float*)d_in[4];
    const float* b_proj = (const float*)d_in[5];
    float* out = (float*)d_out;

    const size_t NC = (size_t)NROWS * C_DIM;       // 8.4M elems
    unsigned short* Qw  = (unsigned short*)d_ws;   // 16MB (Qw||KVw contiguous)
    unsigned short* KVw = Qw  + NC;                // 16MB
    unsigned short* KVt = KVw + NC;                // 16MB [b][h][d][key]
    unsigned short* Xw  = KVt + NC;                // 16MB
    unsigned short* Wqt = Xw  + NC;                // 0.5MB
    unsigned short* Wpt = Wqt + C_DIM * C_DIM;     // 0.5MB

    dim3 blk(256);

    wconv_t2<<<dim3(8, 8, 2), blk, 0, stream>>>(W_qkv, W_proj, Wqt, Wpt);

    // fused Q+KV projection from fp32 F1/F2; KV half also writes KVt
    gemm_bt<1, 1, 1><<<dim3(4, 256), blk, 0, stream>>>(
        nullptr, F1, F2, Wqt, b_qkv, Qw, KVt, SCALE_Q * LOG2E, NROWS);
    cross_attn<<<dim3(16, 4, 8), blk, 0, stream>>>(Qw, KVw, KVt, Xw);
    gemm_bt<0, 0, 0><<<dim3(4, 128), blk, 0, stream>>>(
        Xw, nullptr, nullptr, Wpt, b_proj, out, nullptr, 1.0f, 0);
}